// Round 1
// baseline (162.933 us; speedup 1.0000x reference)
//
#include <hip/hip_runtime.h>
#include <hip/hip_bf16.h>

typedef unsigned short u16;
typedef unsigned long long u64;
typedef __attribute__((ext_vector_type(8))) short short8;   // 8 bf16 (4 VGPRs)
typedef __attribute__((ext_vector_type(4))) float float4v;  // 4 fp32 acc

#define N 8192
#define D 128
#define C 1000
#define TILE 128
#define LDT 136        // padded LDS row stride in bf16 elements (+8 to break bank stride)
#define NW64 (N / 64)  // 128 packed words per class row

// ---------------------------------------------------------------------------
// Kernel A: per-row L2 normalize (write bf16) + exact fp32 proxy term p_i
// one wave per row, lane holds 2 elements
// ---------------------------------------------------------------------------
__global__ void norm_kernel(const float* __restrict__ x, const float* __restrict__ pr,
                            u16* __restrict__ xnb, float* __restrict__ p_out,
                            const float* __restrict__ tp, const float* __restrict__ mp) {
    const int wave = threadIdx.x >> 6;
    const int lane = threadIdx.x & 63;
    const int row  = blockIdx.x * 4 + wave;

    const float2* xr = (const float2*)(x  + (size_t)row * D);
    const float2* prr = (const float2*)(pr + (size_t)row * D);
    float2 xv = xr[lane];
    float2 pv = prr[lane];

    float sx  = xv.x * xv.x + xv.y * xv.y;
    float sp  = pv.x * pv.x + pv.y * pv.y;
    float sxp = xv.x * pv.x + xv.y * pv.y;
    #pragma unroll
    for (int off = 32; off; off >>= 1) {
        sx  += __shfl_xor(sx,  off);
        sp  += __shfl_xor(sp,  off);
        sxp += __shfl_xor(sxp, off);
    }
    float nx = fmaxf(sqrtf(sx), 1e-8f);
    float np = fmaxf(sqrtf(sp), 1e-8f);
    float inv = 1.0f / nx;

    __hip_bfloat16 b0 = __float2bfloat16(xv.x * inv);
    __hip_bfloat16 b1 = __float2bfloat16(xv.y * inv);
    ((__hip_bfloat162*)xnb)[(size_t)row * 64 + lane] = __halves2bfloat162(b0, b1);

    if (lane == 0) {
        float T = tp[0], M = mp[0];
        p_out[row] = __expf((sxp / (nx * np) - M) / T);
    }
}

// ---------------------------------------------------------------------------
// Kernel B: pack negative_mask [N, C] (float 0/1) into bits: packed[l][w] bit j
// one wave per (l, w) pair; lane = j within the 64-word
// ---------------------------------------------------------------------------
__global__ void pack_kernel(const float* __restrict__ nm, u64* __restrict__ packed) {
    const int lane = threadIdx.x & 63;
    const int pair = (blockIdx.x * blockDim.x + threadIdx.x) >> 6; // 0 .. C*NW64-1
    const int l = pair >> 7;       // / NW64(=128)
    const int w = pair & 127;
    const int j = w * 64 + lane;
    float v = nm[(size_t)j * C + l];
    u64 b = __ballot(v > 0.5f);
    if (lane == 0) packed[(size_t)l * NW64 + w] = b;
}

// ---------------------------------------------------------------------------
// Kernel C: fused sim-GEMM (bf16 MFMA) + exp + mask + per-row partial sums
// block = 256 thr (4 waves), tile 128(i) x 128(j), K = D = 128
// grid.x = 64 i-tiles, grid.y = 16 j-splits (4 j-tiles each)
// ---------------------------------------------------------------------------
__global__ __launch_bounds__(256, 2)
void cc_main(const u16* __restrict__ xnb, const int* __restrict__ labels,
             const u64* __restrict__ packed,
             float* __restrict__ den, float* __restrict__ num,
             const float* __restrict__ tp, const float* __restrict__ mp) {
    __shared__ u16 As[TILE * LDT];
    __shared__ u16 Bs[TILE * LDT];
    __shared__ u64 Ms[TILE * 2];
    __shared__ int Lab[TILE];

    const int tid  = threadIdx.x;
    const int lane = tid & 63;
    const int wv   = tid >> 6;
    const int wr   = wv >> 1;      // wave row (0..1) -> 64 i-rows
    const int wc   = wv & 1;       // wave col (0..1) -> 64 j-cols
    const int m0   = lane & 15;
    const int kq   = lane >> 4;    // 0..3
    const int ibase = blockIdx.x * TILE;

    const float T = tp[0];
    const float M = mp[0];
    const float invT = 1.0f / T;

    // stage A tile (128 rows x 128 bf16), each thread 128 B
    {
        int r = tid >> 1, h = tid & 1;
        const uint4* src = (const uint4*)(xnb + (size_t)(ibase + r) * D + h * 64);
        uint4* dst = (uint4*)(As + r * LDT + h * 64);
        #pragma unroll
        for (int q = 0; q < 8; q++) dst[q] = src[q];
        if (tid < TILE) Lab[tid] = labels[ibase + tid];
    }
    __syncthreads();

    float dacc[4][4] = {};  // [tm][reg] per-row denominator partials
    float nacc[4][4] = {};  // numerator partials

    for (int q = 0; q < 4; q++) {
        const int jbase = (blockIdx.y * 4 + q) * TILE;

        // stage B tile + mask words for this j-tile
        {
            int r = tid >> 1, h = tid & 1;
            const uint4* src = (const uint4*)(xnb + (size_t)(jbase + r) * D + h * 64);
            uint4* dst = (uint4*)(Bs + r * LDT + h * 64);
            #pragma unroll
            for (int qq = 0; qq < 8; qq++) dst[qq] = src[qq];
            Ms[r * 2 + h] = packed[(size_t)Lab[r] * NW64 + (jbase >> 6) + h];
        }
        __syncthreads();

        // MFMA: 4x4 grid of 16x16 tiles per wave, K = 128 in 4 steps of 32
        float4v acc[4][4];
        #pragma unroll
        for (int a = 0; a < 4; a++)
            #pragma unroll
            for (int b = 0; b < 4; b++)
                acc[a][b] = (float4v){0.f, 0.f, 0.f, 0.f};

        #pragma unroll
        for (int kk = 0; kk < 4; kk++) {
            const int k0 = kk * 32 + kq * 8;
            short8 a_f[4], b_f[4];
            #pragma unroll
            for (int tm = 0; tm < 4; tm++)
                a_f[tm] = *(const short8*)(As + (wr * 64 + tm * 16 + m0) * LDT + k0);
            #pragma unroll
            for (int tn = 0; tn < 4; tn++)
                b_f[tn] = *(const short8*)(Bs + (wc * 64 + tn * 16 + m0) * LDT + k0);
            #pragma unroll
            for (int tm = 0; tm < 4; tm++)
                #pragma unroll
                for (int tn = 0; tn < 4; tn++)
                    acc[tm][tn] = __builtin_amdgcn_mfma_f32_16x16x32_bf16(
                        a_f[tm], b_f[tn], acc[tm][tn], 0, 0, 0);
        }

        // epilogue: exp, diagonal removal, mask, accumulate per-row partials
        #pragma unroll
        for (int tm = 0; tm < 4; tm++) {
            #pragma unroll
            for (int r = 0; r < 4; r++) {
                const int lrow = wr * 64 + tm * 16 + kq * 4 + r; // C layout: row=(lane>>4)*4+reg
                const int gi = ibase + lrow;
                const u64 w = Ms[lrow * 2 + wc]; // word covering cols [jbase+wc*64, +64)
                #pragma unroll
                for (int tn = 0; tn < 4; tn++) {
                    const int gj = jbase + wc * 64 + tn * 16 + m0; // C layout: col=lane&15
                    float e = __expf((acc[tm][tn][r] - M) * invT);
                    e = (gi == gj) ? 0.0f : e;
                    dacc[tm][r] += e;
                    nacc[tm][r] += ((w >> (tn * 16 + m0)) & 1ull) ? e : 0.0f;
                }
            }
        }
        __syncthreads();  // Ms/Bs reused next iteration
    }

    // reduce across the 16 column-lanes (lane bits 0..3), then atomics
    #pragma unroll
    for (int tm = 0; tm < 4; tm++) {
        #pragma unroll
        for (int r = 0; r < 4; r++) {
            float d = dacc[tm][r], n = nacc[tm][r];
            #pragma unroll
            for (int off = 1; off < 16; off <<= 1) {
                d += __shfl_xor(d, off);
                n += __shfl_xor(n, off);
            }
            if (m0 == 0) {
                const int gi = ibase + wr * 64 + tm * 16 + kq * 4 + r;
                atomicAdd(&den[gi], d);
                atomicAdd(&num[gi], n);
            }
        }
    }
}

// ---------------------------------------------------------------------------
// Kernel D: final loss = mean_i -log(T * (p_i + num_i) / (p_i + den_i))
// single block, 1024 threads
// ---------------------------------------------------------------------------
__global__ void loss_kernel(const float* __restrict__ p, const float* __restrict__ den,
                            const float* __restrict__ num, float* __restrict__ out,
                            const float* __restrict__ tp) {
    __shared__ float red[16];
    const float T = tp[0];
    float s = 0.0f;
    for (int i = threadIdx.x; i < N; i += 1024) {
        float pi = p[i];
        s += -logf(T * (pi + num[i]) / (pi + den[i]));
    }
    #pragma unroll
    for (int off = 32; off; off >>= 1) s += __shfl_xor(s, off);
    const int lane = threadIdx.x & 63, wv = threadIdx.x >> 6;
    if (lane == 0) red[wv] = s;
    __syncthreads();
    if (wv == 0) {
        float t = (lane < 16) ? red[lane] : 0.0f;
        #pragma unroll
        for (int off = 8; off; off >>= 1) t += __shfl_xor(t, off);
        if (lane == 0) out[0] = t / (float)N;
    }
}

// ---------------------------------------------------------------------------
extern "C" void kernel_launch(void* const* d_in, const int* in_sizes, int n_in,
                              void* d_out, int out_size, void* d_ws, size_t ws_size,
                              hipStream_t stream) {
    (void)in_sizes; (void)n_in; (void)out_size; (void)ws_size;
    const float* inst   = (const float*)d_in[0];
    const float* proxy  = (const float*)d_in[1];
    const float* nm     = (const float*)d_in[2];
    const int*   labels = (const int*)d_in[3];
    const float* temp   = (const float*)d_in[4];
    const float* marg   = (const float*)d_in[5];
    float* out = (float*)d_out;

    char* ws = (char*)d_ws;
    u16*   xnb    = (u16*)ws;                         // N*D*2      = 2,097,152 B
    float* p_arr  = (float*)(ws + 2097152);           // N*4        = 32,768 B
    u64*   packed = (u64*)(ws + 2129920);             // C*128*8    = 1,024,000 B
    float* den    = (float*)(ws + 3153920);           // N*4
    float* num    = (float*)(ws + 3186688);           // N*4

    hipMemsetAsync(den, 0, 2 * N * sizeof(float), stream);  // den + num (contiguous)

    norm_kernel<<<N / 4, 256, 0, stream>>>(inst, proxy, xnb, p_arr, temp, marg);
    pack_kernel<<<(C * NW64) / 4, 256, 0, stream>>>(nm, packed);
    cc_main<<<dim3(N / TILE, 16), 256, 0, stream>>>(xnb, labels, packed, den, num, temp, marg);
    loss_kernel<<<1, 1024, 0, stream>>>(p_arr, den, num, out, temp);
}